// Round 13
// baseline (479.330 us; speedup 1.0000x reference)
//
#include <hip/hip_runtime.h>
#include <cstdint>

// ---------------------------------------------------------------------------
// DirGraphSAGE round 21: 64-node fused blocks + merged scan epilogue.
//  r20 won (430us; fused 76.5). Remaining fused marginal cost = W L2 traffic
//  (300MB/dispatch). 64 nodes/block: block reads full 192KB W once, reused
//  across 4 M-tiles -> 150MB. Each 16-lane slot aggregates 4 nodes
//  sequentially (same edge work, better degree averaging). LDS 64x49 uint4 =
//  50KB -> 3 blocks/CU (>= measured 65% occupancy). k_scan_tops folded into
//  k_scan_out (each block redundantly scans <=25 partials; integer-exact).
//  Agg loop + per-element MFMA order unchanged -> absmax bit-identical.
// ---------------------------------------------------------------------------

typedef __bf16 bf16x8 __attribute__((ext_vector_type(8)));
typedef float f32x4 __attribute__((ext_vector_type(4)));

__device__ __forceinline__ unsigned short f2bf(float f) {
  unsigned u = __float_as_uint(f);
  u += 0x7FFFu + ((u >> 16) & 1u);   // round-to-nearest-even
  return (unsigned short)(u >> 16);
}
__device__ __forceinline__ float bflo(unsigned u) { return __uint_as_float(u << 16); }
__device__ __forceinline__ float bfhi(unsigned u) { return __uint_as_float(u & 0xFFFF0000u); }

__device__ __forceinline__ bf16x8 as_bf16x8(uint4 u) {
  union { uint4 u4; bf16x8 b8; } cv; cv.u4 = u; return cv.b8;
}

// prefix for bucket b (0..7) from packed words p12,p34,p56,p7; p0 = 0.
__device__ __forceinline__ unsigned pre8(unsigned a, unsigned b, unsigned c,
                                         unsigned d, int bk) {
  if (bk == 0) return 0u;
  int k = bk - 1;  // 0..6
  unsigned w = (k < 2) ? a : (k < 4) ? b : (k < 6) ? c : d;
  return (k & 1) ? (w >> 16) : (w & 0xFFFFu);
}

// Fused front kernel, 3 roles by blockIdx (r18 version):
//  role E (blk%3==0, blk<3*edgeBlocks): per-(node,bucket) rank atomics
//  role C (other blk < wBase): x -> bf16 row-major xbu
//  role W (blk >= wBase): W -> fragment-major split-bf16 Wfrag[kc][nt][lane]
__global__ __launch_bounds__(256) void k_front(const int* __restrict__ src,
                                               const int* __restrict__ dst,
                                               int* __restrict__ cin_p,
                                               int* __restrict__ cout_p,
                                               unsigned* __restrict__ rank_pk,
                                               int E, int wBase,
                                               const float* __restrict__ x,
                                               unsigned* __restrict__ xbu, int n,
                                               const float* __restrict__ Wa,
                                               const float* __restrict__ Wb,
                                               const float* __restrict__ Wc,
                                               uint4* __restrict__ Ha,
                                               uint4* __restrict__ Hb,
                                               uint4* __restrict__ Hc,
                                               uint4* __restrict__ La,
                                               uint4* __restrict__ Lb,
                                               uint4* __restrict__ Lc) {
  int blk = blockIdx.x;
  if (blk >= wBase) {          // W-conv role: 72 blocks (3 x 24)
    int wblk = blk - wBase;
    int y = wblk / 24;
    int t = (wblk - y * 24) * 256 + threadIdx.x;   // 0..6143 per matrix
    if (t >= 12 * 8 * 64) return;
    const float* W = (y == 0) ? Wa : ((y == 1) ? Wb : Wc);
    uint4* Hf = (y == 0) ? Ha : ((y == 1) ? Hb : Hc);
    uint4* Lf = (y == 0) ? La : ((y == 1) ? Lb : Lc);
    int kc = t >> 9;            // /512
    int rem = t & 511;
    int nt = rem >> 6;
    int lane = rem & 63;
    int q = lane >> 4, lr = lane & 15;
    int j = nt * 16 + lr;
    int ks = (kc * 4 + q) * 8;
    unsigned hu[4], lu[4];
#pragma unroll
    for (int m = 0; m < 4; ++m) {
      float w0 = W[(size_t)(ks + 2 * m) * 128 + j];
      float w1 = W[(size_t)(ks + 2 * m + 1) * 128 + j];
      unsigned short h0 = f2bf(w0), h1 = f2bf(w1);
      float l0 = w0 - __uint_as_float((unsigned)h0 << 16);
      float l1 = w1 - __uint_as_float((unsigned)h1 << 16);
      hu[m] = (unsigned)h0 | ((unsigned)h1 << 16);
      lu[m] = (unsigned)f2bf(l0) | ((unsigned)f2bf(l1) << 16);
    }
    Hf[t] = make_uint4(hu[0], hu[1], hu[2], hu[3]);
    Lf[t] = make_uint4(lu[0], lu[1], lu[2], lu[3]);
  } else if (blk % 3 == 0) {   // edge role
    int e = (blk / 3) * 256 + threadIdx.x;
    if (e >= E) return;
    int s = src[e], d = dst[e];
    int bf = (unsigned)s >> 13;   // bucket of gathered row for fwd list (by dst)
    int bb = (unsigned)d >> 13;   // bucket of gathered row for bwd list (by src)
    unsigned rf = (unsigned)atomicAdd(&cin_p[(size_t)d * 16 + bf], 1);
    unsigned rb = (unsigned)atomicAdd(&cout_p[(size_t)s * 16 + bb], 1);
    rank_pk[e] = (rf & 0xFFFFu) | (rb << 16);
  } else {                     // conv role
    int cb = blk - blk / 3 - 1;
    int idx = cb * 256 + threadIdx.x;  // over n*32 float4s
    if (idx >= n * 32) return;
    float4 xv = ((const float4*)x)[idx];
    unsigned u0 = (unsigned)f2bf(xv.x) | ((unsigned)f2bf(xv.y) << 16);
    unsigned u1 = (unsigned)f2bf(xv.z) | ((unsigned)f2bf(xv.w) << 16);
    ((uint2*)xbu)[idx] = make_uint2(u0, u1);
  }
}

// Compact + scan-partials + rec deg/prefix fields.
// rec line (16 u32): [0]=offf [1]=degs [2..5]=basef p12,p34,p56,p7 [6,7]=pad
//                    [8]=offb [9]=degs [10..13]=baseb [14,15]=pad
__global__ __launch_bounds__(256) void k_compact_part(const int* __restrict__ cin_p,
                                                      const int* __restrict__ cout_p,
                                                      int* __restrict__ cin_d,
                                                      int* __restrict__ cout_d,
                                                      unsigned* __restrict__ rec,
                                                      int* __restrict__ partA,
                                                      int* __restrict__ partB, int n) {
  __shared__ int redA[256], redB[256];
  int t = threadIdx.x;
  int base = blockIdx.x * 2048 + t * 8;
  int sA = 0, sB = 0;
#pragma unroll
  for (int k = 0; k < 8; ++k) {
    int i = base + k;
    if (i < n) {
      unsigned cinv, coutv;
      unsigned f12, f34, f56, f7;
      {
        const int* pf = &cin_p[(size_t)i * 16];
        int c0 = pf[0], c1 = pf[1], c2 = pf[2], c3 = pf[3];
        int c4 = pf[4], c5 = pf[5], c6 = pf[6], c7 = pf[7];
        unsigned run = c0;
        unsigned p1 = run; run += c1; unsigned p2 = run; run += c2;
        unsigned p3 = run; run += c3; unsigned p4 = run; run += c4;
        unsigned p5 = run; run += c5; unsigned p6 = run; run += c6;
        unsigned p7 = run; run += c7;
        cin_d[i] = (int)run;
        sA += (int)run;
        cinv = (run > 65535u) ? 65535u : run;
        f12 = p1 | (p2 << 16); f34 = p3 | (p4 << 16);
        f56 = p5 | (p6 << 16); f7 = p7;
      }
      unsigned b12, b34, b56, b7;
      {
        const int* pf = &cout_p[(size_t)i * 16];
        int c0 = pf[0], c1 = pf[1], c2 = pf[2], c3 = pf[3];
        int c4 = pf[4], c5 = pf[5], c6 = pf[6], c7 = pf[7];
        unsigned run = c0;
        unsigned p1 = run; run += c1; unsigned p2 = run; run += c2;
        unsigned p3 = run; run += c3; unsigned p4 = run; run += c4;
        unsigned p5 = run; run += c5; unsigned p6 = run; run += c6;
        unsigned p7 = run; run += c7;
        cout_d[i] = (int)run;
        sB += (int)run;
        coutv = (run > 65535u) ? 65535u : run;
        b12 = p1 | (p2 << 16); b34 = p3 | (p4 << 16);
        b56 = p5 | (p6 << 16); b7 = p7;
      }
      unsigned degs = cinv | (coutv << 16);
      unsigned* r = &rec[(size_t)i * 16];
      r[1] = degs; r[2] = f12; r[3] = f34; r[4] = f56; r[5] = f7;
      r[9] = degs; r[10] = b12; r[11] = b34; r[12] = b56; r[13] = b7;
    }
  }
  redA[t] = sA; redB[t] = sB;
  __syncthreads();
  for (int o = 128; o > 0; o >>= 1) {
    if (t < o) { redA[t] += redA[t + o]; redB[t] += redB[t + o]; }
    __syncthreads();
  }
  if (t == 0) { partA[blockIdx.x] = redA[0]; partB[blockIdx.x] = redB[0]; }
}

// Scan output (scan_tops folded in): each block redundantly prefix-sums the
// <=25 block partials (integer-exact, a few cycles), then writes dense off
// arrays (for agg) + off fields in rec (for fill).
__global__ __launch_bounds__(256) void k_scan_out(const int* __restrict__ cntA,
                                                  const int* __restrict__ cntB,
                                                  const int* __restrict__ partA,
                                                  const int* __restrict__ partB,
                                                  int* __restrict__ offA,
                                                  int* __restrict__ offB,
                                                  unsigned* __restrict__ rec,
                                                  int n, int nb) {
  const int* cnt = blockIdx.y ? cntB : cntA;
  const int* part = blockIdx.y ? partB : partA;
  int* off = blockIdx.y ? offB : offA;
  int fld = blockIdx.y ? 8 : 0;   // rec word for this direction's off
  __shared__ int ts[256];
  __shared__ int blockpre;
  int t = threadIdx.x;
  if (t == 0) {
    int run = 0;
    for (int i = 0; i < blockIdx.x; ++i) run += part[i];
    blockpre = run;
  }
  int base = blockIdx.x * 2048 + t * 8;
  int v[8];
  int s = 0;
#pragma unroll
  for (int i = 0; i < 8; ++i) {
    int idx = base + i;
    int c = (idx < n) ? cnt[idx] : 0;
    v[i] = s;          // exclusive prefix within thread
    s += c;
  }
  ts[t] = s;
  __syncthreads();
  for (int o = 1; o < 256; o <<= 1) {
    int val = (t >= o) ? ts[t - o] : 0;
    __syncthreads();
    ts[t] += val;
    __syncthreads();
  }
  int blockbase = blockpre + (t ? ts[t - 1] : 0);
#pragma unroll
  for (int i = 0; i < 8; ++i) {
    int idx = base + i;
    if (idx <= n) {
      int val = blockbase + v[i];
      off[idx] = val;   // idx==n writes the total
      if (idx < n) rec[(size_t)idx * 16 + fld] = (unsigned)val;
    }
  }
}

// Atomic-free fill; 2 random 64B line touches per edge (rec[d], rec[s]).
__global__ __launch_bounds__(256) void k_fill(const int* __restrict__ src,
                                              const int* __restrict__ dst,
                                              const unsigned* __restrict__ rank_pk,
                                              const uint4* __restrict__ rec4,
                                              unsigned* __restrict__ epf,
                                              unsigned* __restrict__ epb, int E) {
  int e = blockIdx.x * 256 + threadIdx.x;
  if (e >= E) return;
  int s = src[e], d = dst[e];
  unsigned rp = rank_pk[e];
  int rf = (int)(rp & 0xFFFFu), rb = (int)(rp >> 16);
  int bf = (unsigned)s >> 13, bb = (unsigned)d >> 13;
  uint4 f0 = rec4[(size_t)d * 4 + 0];
  uint4 f1 = rec4[(size_t)d * 4 + 1];
  uint4 b0 = rec4[(size_t)s * 4 + 2];
  uint4 b1 = rec4[(size_t)s * 4 + 3];
  unsigned co = b0.y >> 16;       // cout of s (fwd weight deg)
  unsigned ci = f0.y & 0xFFFFu;   // cin of d (bwd weight deg)
  unsigned pf = pre8(f0.z, f0.w, f1.x, f1.y, bf);
  unsigned pb = pre8(b0.z, b0.w, b1.x, b1.y, bb);
  epf[f0.x + pf + (unsigned)rf] = ((unsigned)s << 16) | co;
  epb[b0.x + pb + (unsigned)rb] = ((unsigned)d << 16) | ci;
}

// Fused aggregation + GEMM. Block = 64 nodes, 512 threads (8 waves).
// Agg: waves 0-3 fwd, 4-7 bwd; each 16-lane slot handles 4 nodes (p=0..3 ->
// local = slot + p*16). LDS A-tile [64 rows][49 uint4]: cols 0-15 xbu,
// 16-31 fwd, 32-47 bwd, 48 pad. After barrier: wave w computes n-tile nt=w
// for all FOUR 16-row M-tiles, loading W (frag-major, L2-resident) once per
// kc into regs and reusing across the 4 M-tiles (W L2 traffic 150MB).
__global__ __launch_bounds__(512) void k_fused(const uint4* __restrict__ xb,
                                               const int* __restrict__ offA,
                                               const unsigned* __restrict__ epA,
                                               const int* __restrict__ offB,
                                               const unsigned* __restrict__ epB,
                                               const uint4* __restrict__ Whf,
                                               const uint4* __restrict__ Wlf,
                                               const float* __restrict__ bias,
                                               unsigned short* __restrict__ outb,
                                               float* __restrict__ outf, int n) {
  __shared__ uint4 sA[64 * 49];   // 50176 B
  int tid = threadIdx.x;
  int w = tid >> 6, lane = tid & 63;
  int gi = lane >> 4, c = lane & 15;
  int blk = blockIdx.x;
  bool isFwd = w < 4;
  const int* off = isFwd ? offA : offB;
  const unsigned* ep = isFwd ? epA : epB;

  // stage this block's 64 xbu rows (A cols 0..15): 512 threads, 2 uint4 each
#pragma unroll
  for (int ph = 0; ph < 2; ++ph) {
    int f = tid + ph * 512;          // 0..1023
    int r = f >> 4, col = f & 15;
    int v = blk * 64 + r;
    sA[r * 49 + col] = (v < n) ? xb[(size_t)v * 16 + col]
                               : make_uint4(0u, 0u, 0u, 0u);
  }

#define AGG_BODY(r_, w_)                                                      \
  acc[0] = fmaf(bflo(r_.x), w_, acc[0]); acc[1] = fmaf(bfhi(r_.x), w_, acc[1]); \
  acc[2] = fmaf(bflo(r_.y), w_, acc[2]); acc[3] = fmaf(bfhi(r_.y), w_, acc[3]); \
  acc[4] = fmaf(bflo(r_.z), w_, acc[4]); acc[5] = fmaf(bfhi(r_.z), w_, acc[5]); \
  acc[6] = fmaf(bflo(r_.w), w_, acc[6]); acc[7] = fmaf(bfhi(r_.w), w_, acc[7]);

  // aggregation: 4 sequential node passes per 16-lane slot
#pragma unroll
  for (int p = 0; p < 4; ++p) {
    int local = (w & 3) * 4 + gi + p * 16;   // 0..63
    int node = blk * 64 + local;
    int i = 0, end = 0;
    if (node < n) { i = off[node]; end = off[node + 1]; }
    float acc[8];
#pragma unroll
    for (int k = 0; k < 8; ++k) acc[k] = 0.f;

    for (; i + 3 < end; i += 4) {
      unsigned e0 = ep[i], e1 = ep[i + 1], e2 = ep[i + 2], e3 = ep[i + 3];
      uint4 r0 = xb[(size_t)(e0 >> 16) * 16 + c];
      uint4 r1 = xb[(size_t)(e1 >> 16) * 16 + c];
      uint4 r2 = xb[(size_t)(e2 >> 16) * 16 + c];
      uint4 r3 = xb[(size_t)(e3 >> 16) * 16 + c];
      float w0 = 1.0f / (float)(e0 & 0xFFFFu);   // IEEE div: bit-exact
      float w1 = 1.0f / (float)(e1 & 0xFFFFu);
      float w2 = 1.0f / (float)(e2 & 0xFFFFu);
      float w3 = 1.0f / (float)(e3 & 0xFFFFu);
      AGG_BODY(r0, w0)
      AGG_BODY(r1, w1)
      AGG_BODY(r2, w2)
      AGG_BODY(r3, w3)
    }
    for (; i < end; ++i) {
      unsigned e0 = ep[i];
      uint4 r0 = xb[(size_t)(e0 >> 16) * 16 + c];
      float w0 = 1.0f / (float)(e0 & 0xFFFFu);
      AGG_BODY(r0, w0)
    }

    uint4 o;
    o.x = (unsigned)f2bf(acc[0]) | ((unsigned)f2bf(acc[1]) << 16);
    o.y = (unsigned)f2bf(acc[2]) | ((unsigned)f2bf(acc[3]) << 16);
    o.z = (unsigned)f2bf(acc[4]) | ((unsigned)f2bf(acc[5]) << 16);
    o.w = (unsigned)f2bf(acc[6]) | ((unsigned)f2bf(acc[7]) << 16);
    sA[local * 49 + (isFwd ? 16 : 32) + c] = o;  // A cols 16-31 fwd / 32-47 bwd
  }
#undef AGG_BODY
  __syncthreads();

  // GEMM phase: wave w -> n-tile nt = w, 4 M-tiles, W loaded once per kc
  int nt = w;
  int lr = lane & 15, q = lane >> 4;
  f32x4 cc[4];
#pragma unroll
  for (int mt = 0; mt < 4; ++mt) cc[mt] = (f32x4){0.f, 0.f, 0.f, 0.f};
  for (int kc = 0; kc < 12; ++kc) {
    size_t wi = (size_t)((kc * 8 + nt) * 64 + lane);
    bf16x8 bh = as_bf16x8(Whf[wi]);
    bf16x8 bl = as_bf16x8(Wlf[wi]);
#pragma unroll
    for (int mt = 0; mt < 4; ++mt) {
      bf16x8 a = as_bf16x8(sA[(mt * 16 + lr) * 49 + kc * 4 + q]);
      cc[mt] = __builtin_amdgcn_mfma_f32_16x16x32_bf16(a, bh, cc[mt], 0, 0, 0);
      cc[mt] = __builtin_amdgcn_mfma_f32_16x16x32_bf16(a, bl, cc[mt], 0, 0, 0);
    }
  }

  // Epilogue. C layout: col = lane&15, row = (lane>>4)*4 + reg (m89-verified)
  float bv = bias[nt * 16 + lr];
  int colg = nt * 16 + lr;
#pragma unroll
  for (int mt = 0; mt < 4; ++mt) {
#pragma unroll
    for (int reg = 0; reg < 4; ++reg) {
      int row = blk * 64 + mt * 16 + q * 4 + reg;
      if (row >= n) continue;
      if (outb) {
        float t = fmaxf(cc[mt][reg] + bv, 0.f);
        outb[(size_t)row * 128 + colg] = f2bf(t);
      } else {
        outf[(size_t)row * 128 + colg] = cc[mt][reg] + bv;
      }
    }
  }
}

extern "C" void kernel_launch(void* const* d_in, const int* in_sizes, int n_in,
                              void* d_out, int out_size, void* d_ws, size_t ws_size,
                              hipStream_t stream) {
  const int D = 128;
  const int N = in_sizes[0] / D;
  const int E = in_sizes[7];

  const float* x  = (const float*)d_in[0];
  const float* W0 = (const float*)d_in[1];
  const float* b0 = (const float*)d_in[2];
  const float* W1 = (const float*)d_in[3];
  const float* b1 = (const float*)d_in[4];
  const float* W2 = (const float*)d_in[5];
  const float* b2 = (const float*)d_in[6];
  const int* src  = (const int*)d_in[7];
  const int* dst  = (const int*)d_in[8];
  float* out = (float*)d_out;

  char* p = (char*)d_ws;
  auto alloc = [&](size_t bytes) -> char* {
    char* r = p;
    p += (bytes + 15) & ~(size_t)15;
    return r;
  };
  int* cin_p  = (int*)alloc((size_t)N * 64);   // padded: 8 bucket slots / 64B line
  int* cout_p = (int*)alloc((size_t)N * 64);
  int* cin_d  = (int*)alloc((size_t)N * 4);    // dense totals for scan
  int* cout_d = (int*)alloc((size_t)N * 4);
  int* offf = (int*)alloc((size_t)(N + 1) * 4);
  int* offb = (int*)alloc((size_t)(N + 1) * 4);
  unsigned* rec = (unsigned*)alloc((size_t)N * 64);  // 64B fill record / node
  unsigned* rank_pk = (unsigned*)alloc((size_t)E * 4);   // rankf | rankb<<16
  unsigned* epf = (unsigned*)alloc((size_t)E * 4);       // (u<<16 | deg) payload
  unsigned* epb = (unsigned*)alloc((size_t)E * 4);
  unsigned* xbuA = (unsigned*)alloc((size_t)N * 64 * 4); // double-buffered bf16 x
  unsigned* xbuB = (unsigned*)alloc((size_t)N * 64 * 4);
  uint4* Whf[3], *Wlf[3];                     // fragment-major split-bf16 W
  for (int l = 0; l < 3; ++l) {
    Whf[l] = (uint4*)alloc((size_t)12 * 8 * 64 * 16);
    Wlf[l] = (uint4*)alloc((size_t)12 * 8 * 64 * 16);
  }
  int nbScan = (N + 1 + 2047) / 2048;
  int* partA = (int*)alloc((size_t)(nbScan + 1) * 4);
  int* partB = (int*)alloc((size_t)(nbScan + 1) * 4);

  hipMemsetAsync(cin_p, 0, (size_t)2 * N * 64, stream);  // cin_p+cout_p contiguous

  int edgeBlocks = (E + 255) / 256;
  int convBlocks = (N * 32 + 255) / 256;
  int wBase = edgeBlocks + convBlocks + 2;   // edge+conv interleave region
  int fusedBlocks = wBase + 72;              // + 3x24 frag-major wconv blocks
  k_front<<<fusedBlocks, 256, 0, stream>>>(src, dst, cin_p, cout_p, rank_pk,
                                           E, wBase, x, xbuA, N,
                                           W0, W1, W2,
                                           Whf[0], Whf[1], Whf[2],
                                           Wlf[0], Wlf[1], Wlf[2]);
  k_compact_part<<<nbScan, 256, 0, stream>>>(cin_p, cout_p, cin_d, cout_d,
                                             rec, partA, partB, N);
  k_scan_out<<<dim3(nbScan, 2), 256, 0, stream>>>(cin_d, cout_d, partA, partB,
                                                  offf, offb, rec, N, nbScan);
  k_fill<<<(E + 255) / 256, 256, 0, stream>>>(src, dst, rank_pk,
                                              (const uint4*)rec, epf, epb, E);

  const float* bs[3] = {b0, b1, b2};
  int fuseBlocks = (N + 63) / 64;   // 64 nodes/block, 512 threads

  // layer 0: xbuA -> xbuB ; layer 1: xbuB -> xbuA ; layer 2: xbuA -> out(fp32)
  k_fused<<<fuseBlocks, 512, 0, stream>>>(
      (const uint4*)xbuA, offf, epf, offb, epb, Whf[0], Wlf[0], bs[0],
      (unsigned short*)xbuB, nullptr, N);
  k_fused<<<fuseBlocks, 512, 0, stream>>>(
      (const uint4*)xbuB, offf, epf, offb, epb, Whf[1], Wlf[1], bs[1],
      (unsigned short*)xbuA, nullptr, N);
  k_fused<<<fuseBlocks, 512, 0, stream>>>(
      (const uint4*)xbuA, offf, epf, offb, epb, Whf[2], Wlf[2], bs[2],
      nullptr, out, N);
}

// Round 14
// 427.266 us; speedup vs baseline: 1.1219x; 1.1219x over previous
//
#include <hip/hip_runtime.h>
#include <cstdint>

// ---------------------------------------------------------------------------
// DirGraphSAGE round 22: REVERT to r20's 32-node fused kernel (proven 430us);
//  keep r21's merged scan epilogue (scan_tops folded into scan_out, exact).
//  r21 post-mortem: 64-node blocks dropped occupancy 65->43% (VGPR 40,
//  SGPR 112, 50KB LDS -> ~2 blocks/CU) and the latency-sensitive gather fell
//  3.1->2.4 TB/s; the 150MB W-traffic saving (~4us) couldn't pay for it.
//  W-reuse curve is occupancy-optimal at 32 nodes/block.
// ---------------------------------------------------------------------------

typedef __bf16 bf16x8 __attribute__((ext_vector_type(8)));
typedef float f32x4 __attribute__((ext_vector_type(4)));

__device__ __forceinline__ unsigned short f2bf(float f) {
  unsigned u = __float_as_uint(f);
  u += 0x7FFFu + ((u >> 16) & 1u);   // round-to-nearest-even
  return (unsigned short)(u >> 16);
}
__device__ __forceinline__ float bflo(unsigned u) { return __uint_as_float(u << 16); }
__device__ __forceinline__ float bfhi(unsigned u) { return __uint_as_float(u & 0xFFFF0000u); }

__device__ __forceinline__ bf16x8 as_bf16x8(uint4 u) {
  union { uint4 u4; bf16x8 b8; } cv; cv.u4 = u; return cv.b8;
}

// prefix for bucket b (0..7) from packed words p12,p34,p56,p7; p0 = 0.
__device__ __forceinline__ unsigned pre8(unsigned a, unsigned b, unsigned c,
                                         unsigned d, int bk) {
  if (bk == 0) return 0u;
  int k = bk - 1;  // 0..6
  unsigned w = (k < 2) ? a : (k < 4) ? b : (k < 6) ? c : d;
  return (k & 1) ? (w >> 16) : (w & 0xFFFFu);
}

// Fused front kernel, 3 roles by blockIdx (r18 version):
//  role E (blk%3==0, blk<3*edgeBlocks): per-(node,bucket) rank atomics
//  role C (other blk < wBase): x -> bf16 row-major xbu
//  role W (blk >= wBase): W -> fragment-major split-bf16 Wfrag[kc][nt][lane]
__global__ __launch_bounds__(256) void k_front(const int* __restrict__ src,
                                               const int* __restrict__ dst,
                                               int* __restrict__ cin_p,
                                               int* __restrict__ cout_p,
                                               unsigned* __restrict__ rank_pk,
                                               int E, int wBase,
                                               const float* __restrict__ x,
                                               unsigned* __restrict__ xbu, int n,
                                               const float* __restrict__ Wa,
                                               const float* __restrict__ Wb,
                                               const float* __restrict__ Wc,
                                               uint4* __restrict__ Ha,
                                               uint4* __restrict__ Hb,
                                               uint4* __restrict__ Hc,
                                               uint4* __restrict__ La,
                                               uint4* __restrict__ Lb,
                                               uint4* __restrict__ Lc) {
  int blk = blockIdx.x;
  if (blk >= wBase) {          // W-conv role: 72 blocks (3 x 24)
    int wblk = blk - wBase;
    int y = wblk / 24;
    int t = (wblk - y * 24) * 256 + threadIdx.x;   // 0..6143 per matrix
    if (t >= 12 * 8 * 64) return;
    const float* W = (y == 0) ? Wa : ((y == 1) ? Wb : Wc);
    uint4* Hf = (y == 0) ? Ha : ((y == 1) ? Hb : Hc);
    uint4* Lf = (y == 0) ? La : ((y == 1) ? Lb : Lc);
    int kc = t >> 9;            // /512
    int rem = t & 511;
    int nt = rem >> 6;
    int lane = rem & 63;
    int q = lane >> 4, lr = lane & 15;
    int j = nt * 16 + lr;
    int ks = (kc * 4 + q) * 8;
    unsigned hu[4], lu[4];
#pragma unroll
    for (int m = 0; m < 4; ++m) {
      float w0 = W[(size_t)(ks + 2 * m) * 128 + j];
      float w1 = W[(size_t)(ks + 2 * m + 1) * 128 + j];
      unsigned short h0 = f2bf(w0), h1 = f2bf(w1);
      float l0 = w0 - __uint_as_float((unsigned)h0 << 16);
      float l1 = w1 - __uint_as_float((unsigned)h1 << 16);
      hu[m] = (unsigned)h0 | ((unsigned)h1 << 16);
      lu[m] = (unsigned)f2bf(l0) | ((unsigned)f2bf(l1) << 16);
    }
    Hf[t] = make_uint4(hu[0], hu[1], hu[2], hu[3]);
    Lf[t] = make_uint4(lu[0], lu[1], lu[2], lu[3]);
  } else if (blk % 3 == 0) {   // edge role
    int e = (blk / 3) * 256 + threadIdx.x;
    if (e >= E) return;
    int s = src[e], d = dst[e];
    int bf = (unsigned)s >> 13;   // bucket of gathered row for fwd list (by dst)
    int bb = (unsigned)d >> 13;   // bucket of gathered row for bwd list (by src)
    unsigned rf = (unsigned)atomicAdd(&cin_p[(size_t)d * 16 + bf], 1);
    unsigned rb = (unsigned)atomicAdd(&cout_p[(size_t)s * 16 + bb], 1);
    rank_pk[e] = (rf & 0xFFFFu) | (rb << 16);
  } else {                     // conv role
    int cb = blk - blk / 3 - 1;
    int idx = cb * 256 + threadIdx.x;  // over n*32 float4s
    if (idx >= n * 32) return;
    float4 xv = ((const float4*)x)[idx];
    unsigned u0 = (unsigned)f2bf(xv.x) | ((unsigned)f2bf(xv.y) << 16);
    unsigned u1 = (unsigned)f2bf(xv.z) | ((unsigned)f2bf(xv.w) << 16);
    ((uint2*)xbu)[idx] = make_uint2(u0, u1);
  }
}

// Compact + scan-partials + rec deg/prefix fields.
// rec line (16 u32): [0]=offf [1]=degs [2..5]=basef p12,p34,p56,p7 [6,7]=pad
//                    [8]=offb [9]=degs [10..13]=baseb [14,15]=pad
__global__ __launch_bounds__(256) void k_compact_part(const int* __restrict__ cin_p,
                                                      const int* __restrict__ cout_p,
                                                      int* __restrict__ cin_d,
                                                      int* __restrict__ cout_d,
                                                      unsigned* __restrict__ rec,
                                                      int* __restrict__ partA,
                                                      int* __restrict__ partB, int n) {
  __shared__ int redA[256], redB[256];
  int t = threadIdx.x;
  int base = blockIdx.x * 2048 + t * 8;
  int sA = 0, sB = 0;
#pragma unroll
  for (int k = 0; k < 8; ++k) {
    int i = base + k;
    if (i < n) {
      unsigned cinv, coutv;
      unsigned f12, f34, f56, f7;
      {
        const int* pf = &cin_p[(size_t)i * 16];
        int c0 = pf[0], c1 = pf[1], c2 = pf[2], c3 = pf[3];
        int c4 = pf[4], c5 = pf[5], c6 = pf[6], c7 = pf[7];
        unsigned run = c0;
        unsigned p1 = run; run += c1; unsigned p2 = run; run += c2;
        unsigned p3 = run; run += c3; unsigned p4 = run; run += c4;
        unsigned p5 = run; run += c5; unsigned p6 = run; run += c6;
        unsigned p7 = run; run += c7;
        cin_d[i] = (int)run;
        sA += (int)run;
        cinv = (run > 65535u) ? 65535u : run;
        f12 = p1 | (p2 << 16); f34 = p3 | (p4 << 16);
        f56 = p5 | (p6 << 16); f7 = p7;
      }
      unsigned b12, b34, b56, b7;
      {
        const int* pf = &cout_p[(size_t)i * 16];
        int c0 = pf[0], c1 = pf[1], c2 = pf[2], c3 = pf[3];
        int c4 = pf[4], c5 = pf[5], c6 = pf[6], c7 = pf[7];
        unsigned run = c0;
        unsigned p1 = run; run += c1; unsigned p2 = run; run += c2;
        unsigned p3 = run; run += c3; unsigned p4 = run; run += c4;
        unsigned p5 = run; run += c5; unsigned p6 = run; run += c6;
        unsigned p7 = run; run += c7;
        cout_d[i] = (int)run;
        sB += (int)run;
        coutv = (run > 65535u) ? 65535u : run;
        b12 = p1 | (p2 << 16); b34 = p3 | (p4 << 16);
        b56 = p5 | (p6 << 16); b7 = p7;
      }
      unsigned degs = cinv | (coutv << 16);
      unsigned* r = &rec[(size_t)i * 16];
      r[1] = degs; r[2] = f12; r[3] = f34; r[4] = f56; r[5] = f7;
      r[9] = degs; r[10] = b12; r[11] = b34; r[12] = b56; r[13] = b7;
    }
  }
  redA[t] = sA; redB[t] = sB;
  __syncthreads();
  for (int o = 128; o > 0; o >>= 1) {
    if (t < o) { redA[t] += redA[t + o]; redB[t] += redB[t + o]; }
    __syncthreads();
  }
  if (t == 0) { partA[blockIdx.x] = redA[0]; partB[blockIdx.x] = redB[0]; }
}

// Scan output (scan_tops folded in): each block redundantly prefix-sums the
// <=25 block partials (integer-exact, a few cycles), then writes dense off
// arrays (for agg) + off fields in rec (for fill).
__global__ __launch_bounds__(256) void k_scan_out(const int* __restrict__ cntA,
                                                  const int* __restrict__ cntB,
                                                  const int* __restrict__ partA,
                                                  const int* __restrict__ partB,
                                                  int* __restrict__ offA,
                                                  int* __restrict__ offB,
                                                  unsigned* __restrict__ rec,
                                                  int n, int nb) {
  const int* cnt = blockIdx.y ? cntB : cntA;
  const int* part = blockIdx.y ? partB : partA;
  int* off = blockIdx.y ? offB : offA;
  int fld = blockIdx.y ? 8 : 0;   // rec word for this direction's off
  __shared__ int ts[256];
  __shared__ int blockpre;
  int t = threadIdx.x;
  if (t == 0) {
    int run = 0;
    for (int i = 0; i < blockIdx.x; ++i) run += part[i];
    blockpre = run;
  }
  int base = blockIdx.x * 2048 + t * 8;
  int v[8];
  int s = 0;
#pragma unroll
  for (int i = 0; i < 8; ++i) {
    int idx = base + i;
    int c = (idx < n) ? cnt[idx] : 0;
    v[i] = s;          // exclusive prefix within thread
    s += c;
  }
  ts[t] = s;
  __syncthreads();
  for (int o = 1; o < 256; o <<= 1) {
    int val = (t >= o) ? ts[t - o] : 0;
    __syncthreads();
    ts[t] += val;
    __syncthreads();
  }
  int blockbase = blockpre + (t ? ts[t - 1] : 0);
#pragma unroll
  for (int i = 0; i < 8; ++i) {
    int idx = base + i;
    if (idx <= n) {
      int val = blockbase + v[i];
      off[idx] = val;   // idx==n writes the total
      if (idx < n) rec[(size_t)idx * 16 + fld] = (unsigned)val;
    }
  }
}

// Atomic-free fill; 2 random 64B line touches per edge (rec[d], rec[s]).
__global__ __launch_bounds__(256) void k_fill(const int* __restrict__ src,
                                              const int* __restrict__ dst,
                                              const unsigned* __restrict__ rank_pk,
                                              const uint4* __restrict__ rec4,
                                              unsigned* __restrict__ epf,
                                              unsigned* __restrict__ epb, int E) {
  int e = blockIdx.x * 256 + threadIdx.x;
  if (e >= E) return;
  int s = src[e], d = dst[e];
  unsigned rp = rank_pk[e];
  int rf = (int)(rp & 0xFFFFu), rb = (int)(rp >> 16);
  int bf = (unsigned)s >> 13, bb = (unsigned)d >> 13;
  uint4 f0 = rec4[(size_t)d * 4 + 0];
  uint4 f1 = rec4[(size_t)d * 4 + 1];
  uint4 b0 = rec4[(size_t)s * 4 + 2];
  uint4 b1 = rec4[(size_t)s * 4 + 3];
  unsigned co = b0.y >> 16;       // cout of s (fwd weight deg)
  unsigned ci = f0.y & 0xFFFFu;   // cin of d (bwd weight deg)
  unsigned pf = pre8(f0.z, f0.w, f1.x, f1.y, bf);
  unsigned pb = pre8(b0.z, b0.w, b1.x, b1.y, bb);
  epf[f0.x + pf + (unsigned)rf] = ((unsigned)s << 16) | co;
  epb[b0.x + pb + (unsigned)rb] = ((unsigned)d << 16) | ci;
}

// Fused aggregation + GEMM. Block = 32 nodes, 512 threads (8 waves).
// Agg: waves 0-3 fwd, 4-7 bwd; each 16-lane slot handles 2 nodes (passes
// p=0,1 -> local, local+16). LDS A-tile [32 rows][49 uint4]: cols 0-15 xbu,
// 16-31 fwd, 32-47 bwd, 48 pad. After barrier: wave w computes n-tile nt=w
// for BOTH 16-row M-tiles, loading W (frag-major, L2-resident) once per kc
// into regs and reusing across the 2 M-tiles (halves W L2 traffic).
__global__ __launch_bounds__(512) void k_fused(const uint4* __restrict__ xb,
                                               const int* __restrict__ offA,
                                               const unsigned* __restrict__ epA,
                                               const int* __restrict__ offB,
                                               const unsigned* __restrict__ epB,
                                               const uint4* __restrict__ Whf,
                                               const uint4* __restrict__ Wlf,
                                               const float* __restrict__ bias,
                                               unsigned short* __restrict__ outb,
                                               float* __restrict__ outf, int n) {
  __shared__ uint4 sA[32 * 49];   // 25088 B
  int tid = threadIdx.x;
  int w = tid >> 6, lane = tid & 63;
  int gi = lane >> 4, c = lane & 15;
  int blk = blockIdx.x;
  bool isFwd = w < 4;
  const int* off = isFwd ? offA : offB;
  const unsigned* ep = isFwd ? epA : epB;

  // stage this block's 32 xbu rows (A cols 0..15): 512 threads, 1 uint4 each
  {
    int r = tid >> 4, col = tid & 15;
    int v = blk * 32 + r;
    sA[r * 49 + col] = (v < n) ? xb[(size_t)v * 16 + col]
                               : make_uint4(0u, 0u, 0u, 0u);
  }

#define AGG_BODY(r_, w_)                                                      \
  acc[0] = fmaf(bflo(r_.x), w_, acc[0]); acc[1] = fmaf(bfhi(r_.x), w_, acc[1]); \
  acc[2] = fmaf(bflo(r_.y), w_, acc[2]); acc[3] = fmaf(bfhi(r_.y), w_, acc[3]); \
  acc[4] = fmaf(bflo(r_.z), w_, acc[4]); acc[5] = fmaf(bfhi(r_.z), w_, acc[5]); \
  acc[6] = fmaf(bflo(r_.w), w_, acc[6]); acc[7] = fmaf(bfhi(r_.w), w_, acc[7]);

  // aggregation: 2 sequential node passes per 16-lane slot
#pragma unroll
  for (int p = 0; p < 2; ++p) {
    int local = (w & 3) * 4 + gi + p * 16;   // 0..31
    int node = blk * 32 + local;
    int i = 0, end = 0;
    if (node < n) { i = off[node]; end = off[node + 1]; }
    float acc[8];
#pragma unroll
    for (int k = 0; k < 8; ++k) acc[k] = 0.f;

    for (; i + 3 < end; i += 4) {
      unsigned e0 = ep[i], e1 = ep[i + 1], e2 = ep[i + 2], e3 = ep[i + 3];
      uint4 r0 = xb[(size_t)(e0 >> 16) * 16 + c];
      uint4 r1 = xb[(size_t)(e1 >> 16) * 16 + c];
      uint4 r2 = xb[(size_t)(e2 >> 16) * 16 + c];
      uint4 r3 = xb[(size_t)(e3 >> 16) * 16 + c];
      float w0 = 1.0f / (float)(e0 & 0xFFFFu);   // IEEE div: bit-exact
      float w1 = 1.0f / (float)(e1 & 0xFFFFu);
      float w2 = 1.0f / (float)(e2 & 0xFFFFu);
      float w3 = 1.0f / (float)(e3 & 0xFFFFu);
      AGG_BODY(r0, w0)
      AGG_BODY(r1, w1)
      AGG_BODY(r2, w2)
      AGG_BODY(r3, w3)
    }
    for (; i < end; ++i) {
      unsigned e0 = ep[i];
      uint4 r0 = xb[(size_t)(e0 >> 16) * 16 + c];
      float w0 = 1.0f / (float)(e0 & 0xFFFFu);
      AGG_BODY(r0, w0)
    }

    uint4 o;
    o.x = (unsigned)f2bf(acc[0]) | ((unsigned)f2bf(acc[1]) << 16);
    o.y = (unsigned)f2bf(acc[2]) | ((unsigned)f2bf(acc[3]) << 16);
    o.z = (unsigned)f2bf(acc[4]) | ((unsigned)f2bf(acc[5]) << 16);
    o.w = (unsigned)f2bf(acc[6]) | ((unsigned)f2bf(acc[7]) << 16);
    sA[local * 49 + (isFwd ? 16 : 32) + c] = o;  // A cols 16-31 fwd / 32-47 bwd
  }
#undef AGG_BODY
  __syncthreads();

  // GEMM phase: wave w -> n-tile nt = w, both M-tiles, W loaded once per kc
  int nt = w;
  int lr = lane & 15, q = lane >> 4;
  f32x4 c0 = (f32x4){0.f, 0.f, 0.f, 0.f};
  f32x4 c1 = (f32x4){0.f, 0.f, 0.f, 0.f};
  for (int kc = 0; kc < 12; ++kc) {
    size_t wi = (size_t)((kc * 8 + nt) * 64 + lane);
    bf16x8 bh = as_bf16x8(Whf[wi]);
    bf16x8 bl = as_bf16x8(Wlf[wi]);
    bf16x8 a0 = as_bf16x8(sA[(0 * 16 + lr) * 49 + kc * 4 + q]);
    bf16x8 a1 = as_bf16x8(sA[(1 * 16 + lr) * 49 + kc * 4 + q]);
    c0 = __builtin_amdgcn_mfma_f32_16x16x32_bf16(a0, bh, c0, 0, 0, 0);
    c0 = __builtin_amdgcn_mfma_f32_16x16x32_bf16(a0, bl, c0, 0, 0, 0);
    c1 = __builtin_amdgcn_mfma_f32_16x16x32_bf16(a1, bh, c1, 0, 0, 0);
    c1 = __builtin_amdgcn_mfma_f32_16x16x32_bf16(a1, bl, c1, 0, 0, 0);
  }

  // Epilogue. C layout: col = lane&15, row = (lane>>4)*4 + reg (m89-verified)
  float bv = bias[nt * 16 + lr];
  int colg = nt * 16 + lr;
#pragma unroll
  for (int mt = 0; mt < 2; ++mt) {
    f32x4 cc = mt ? c1 : c0;
#pragma unroll
    for (int reg = 0; reg < 4; ++reg) {
      int row = blk * 32 + mt * 16 + q * 4 + reg;
      if (row >= n) continue;
      if (outb) {
        float t = fmaxf(cc[reg] + bv, 0.f);
        outb[(size_t)row * 128 + colg] = f2bf(t);
      } else {
        outf[(size_t)row * 128 + colg] = cc[reg] + bv;
      }
    }
  }
}

extern "C" void kernel_launch(void* const* d_in, const int* in_sizes, int n_in,
                              void* d_out, int out_size, void* d_ws, size_t ws_size,
                              hipStream_t stream) {
  const int D = 128;
  const int N = in_sizes[0] / D;
  const int E = in_sizes[7];

  const float* x  = (const float*)d_in[0];
  const float* W0 = (const float*)d_in[1];
  const float* b0 = (const float*)d_in[2];
  const float* W1 = (const float*)d_in[3];
  const float* b1 = (const float*)d_in[4];
  const float* W2 = (const float*)d_in[5];
  const float* b2 = (const float*)d_in[6];
  const int* src  = (const int*)d_in[7];
  const int* dst  = (const int*)d_in[8];
  float* out = (float*)d_out;

  char* p = (char*)d_ws;
  auto alloc = [&](size_t bytes) -> char* {
    char* r = p;
    p += (bytes + 15) & ~(size_t)15;
    return r;
  };
  int* cin_p  = (int*)alloc((size_t)N * 64);   // padded: 8 bucket slots / 64B line
  int* cout_p = (int*)alloc((size_t)N * 64);
  int* cin_d  = (int*)alloc((size_t)N * 4);    // dense totals for scan
  int* cout_d = (int*)alloc((size_t)N * 4);
  int* offf = (int*)alloc((size_t)(N + 1) * 4);
  int* offb = (int*)alloc((size_t)(N + 1) * 4);
  unsigned* rec = (unsigned*)alloc((size_t)N * 64);  // 64B fill record / node
  unsigned* rank_pk = (unsigned*)alloc((size_t)E * 4);   // rankf | rankb<<16
  unsigned* epf = (unsigned*)alloc((size_t)E * 4);       // (u<<16 | deg) payload
  unsigned* epb = (unsigned*)alloc((size_t)E * 4);
  unsigned* xbuA = (unsigned*)alloc((size_t)N * 64 * 4); // double-buffered bf16 x
  unsigned* xbuB = (unsigned*)alloc((size_t)N * 64 * 4);
  uint4* Whf[3], *Wlf[3];                     // fragment-major split-bf16 W
  for (int l = 0; l < 3; ++l) {
    Whf[l] = (uint4*)alloc((size_t)12 * 8 * 64 * 16);
    Wlf[l] = (uint4*)alloc((size_t)12 * 8 * 64 * 16);
  }
  int nbScan = (N + 1 + 2047) / 2048;
  int* partA = (int*)alloc((size_t)(nbScan + 1) * 4);
  int* partB = (int*)alloc((size_t)(nbScan + 1) * 4);

  hipMemsetAsync(cin_p, 0, (size_t)2 * N * 64, stream);  // cin_p+cout_p contiguous

  int edgeBlocks = (E + 255) / 256;
  int convBlocks = (N * 32 + 255) / 256;
  int wBase = edgeBlocks + convBlocks + 2;   // edge+conv interleave region
  int fusedBlocks = wBase + 72;              // + 3x24 frag-major wconv blocks
  k_front<<<fusedBlocks, 256, 0, stream>>>(src, dst, cin_p, cout_p, rank_pk,
                                           E, wBase, x, xbuA, N,
                                           W0, W1, W2,
                                           Whf[0], Whf[1], Whf[2],
                                           Wlf[0], Wlf[1], Wlf[2]);
  k_compact_part<<<nbScan, 256, 0, stream>>>(cin_p, cout_p, cin_d, cout_d,
                                             rec, partA, partB, N);
  k_scan_out<<<dim3(nbScan, 2), 256, 0, stream>>>(cin_d, cout_d, partA, partB,
                                                  offf, offb, rec, N, nbScan);
  k_fill<<<(E + 255) / 256, 256, 0, stream>>>(src, dst, rank_pk,
                                              (const uint4*)rec, epf, epb, E);

  const float* bs[3] = {b0, b1, b2};
  int fuseBlocks = (N + 31) / 32;   // 32 nodes/block, 512 threads

  // layer 0: xbuA -> xbuB ; layer 1: xbuB -> xbuA ; layer 2: xbuA -> out(fp32)
  k_fused<<<fuseBlocks, 512, 0, stream>>>(
      (const uint4*)xbuA, offf, epf, offb, epb, Whf[0], Wlf[0], bs[0],
      (unsigned short*)xbuB, nullptr, N);
  k_fused<<<fuseBlocks, 512, 0, stream>>>(
      (const uint4*)xbuB, offf, epf, offb, epb, Whf[1], Wlf[1], bs[1],
      (unsigned short*)xbuA, nullptr, N);
  k_fused<<<fuseBlocks, 512, 0, stream>>>(
      (const uint4*)xbuA, offf, epf, offb, epb, Whf[2], Wlf[2], bs[2],
      nullptr, out, N);
}